// Round 5
// baseline (330.234 us; speedup 1.0000x reference)
//
#include <hip/hip_runtime.h>

// DynamicExpertGating: routed MoE on MI355X (gfx950)
//   tokens T=8192 (B4 x S2048), H=1024, D=1024, E=8, top-2
// R9: expert_gemm ported to the verified 8-phase 256^2 schedule
//   (T2 swizzle + T3/T4 counted-vmcnt phases + T5 setprio; cf. m248
//   grouped-GEMM 848 TF @ K=1024 vs our 412 TF 2-phase).
//   Geometry: BM=BN=256, BK=64, 8 waves (2m x 4n), LDS 128KB
//   (2 K-tiles x 2 k-half granules x {A,B} x 256x32 bf16).
//   Per K-tile: 4 phases (k-half x m-half), 16 MFMA each; 1 granule
//   staged per phase, 6-phase lead; waits vmcnt(4) @p1-end,
//   vmcnt(8) @p3-end placed BEFORE the trailing barrier so the
//   per-wave counted wait + barrier publishes all waves' staged data
//   (vmcnt(0) at t=15 mid since nothing newer is staged).
//   LDS bank fix: chunk ^= (row&3) XOR swizzle, inverse on the global
//   source, forward on ds_read (rule: both-sides-or-neither).
//   Other kernels byte-identical to R8.
//
// ws layout (bytes):
//   [0,16M)   x_bf16 [8192][1024] (reused as combined bf16 later)
//   [16M,32M) weT [8][1024 d][1024 h] bf16 ; [32M,34M) woT bf16
//   [34M,66M) outE [16384 packed rows][1024] bf16
//   [66M+..]  counts[8], tok2[8][8192], wlist[8][8192], eidx[16384],
//             ew[16384] (reused as s2p after build_lists)

#define TOKENS 8192
#define HDIM   1024
#define DDIM   1024
#define NEXP   8

typedef __bf16 bf16x8 __attribute__((ext_vector_type(8)));
typedef float  f32x4  __attribute__((ext_vector_type(4)));

__device__ __forceinline__ unsigned short f2b(float f) {
  unsigned int u = __builtin_bit_cast(unsigned int, f);
  u = u + 0x7fffu + ((u >> 16) & 1u);
  return (unsigned short)(u >> 16);
}
__device__ __forceinline__ float b2f(unsigned short b) {
  unsigned int u = ((unsigned int)b) << 16;
  return __builtin_bit_cast(float, u);
}

__device__ __forceinline__ void gld_lds16(const void* g, void* l) {
  __builtin_amdgcn_global_load_lds(
      (__attribute__((address_space(1))) void*)(g),
      (__attribute__((address_space(3))) void*)(l),
      16, 0, 0);
}

// ---------------- weight transpose+convert ----------------

__global__ void transpose_cvt_kernel(const float* __restrict__ we, const float* __restrict__ wo,
                                     unsigned short* __restrict__ weT, unsigned short* __restrict__ woT) {
  __shared__ unsigned short tile[32][33];
  int z = blockIdx.z;
  const float* s;
  unsigned short* d;
  if (z < 8) { s = we + (size_t)z * HDIM * DDIM; d = weT + (size_t)z * HDIM * DDIM; }
  else       { s = wo;                            d = woT; }
  int bx = blockIdx.x * 32;
  int by = blockIdx.y * 32;
  for (int i = threadIdx.y; i < 32; i += 8)
    tile[i][threadIdx.x] = f2b(s[(size_t)(by + i) * 1024 + bx + threadIdx.x]);
  __syncthreads();
  for (int i = threadIdx.y; i < 32; i += 8)
    d[(size_t)(bx + i) * 1024 + by + threadIdx.x] = tile[threadIdx.x][i];
}

// ---------------- router pass 1 ----------------

__global__ void router_compute_kernel(const float* __restrict__ x, const float* __restrict__ wr,
                                      const float* __restrict__ br,
                                      int* __restrict__ eidx, float* __restrict__ ew,
                                      unsigned short* __restrict__ xb) {
  int wave = threadIdx.x >> 6, lane = threadIdx.x & 63;
  int t = blockIdx.x * 4 + wave;
  const float* xp = x + (size_t)t * HDIM;
  unsigned short* xbp = xb + (size_t)t * HDIM;
  float acc[8];
#pragma unroll
  for (int e = 0; e < 8; ++e) acc[e] = 0.f;
#pragma unroll
  for (int h0 = 0; h0 < HDIM; h0 += 256) {
    int h = h0 + lane * 4;
    float4 xv = *(const float4*)&xp[h];
    ushort4 o;
    o.x = f2b(xv.x); o.y = f2b(xv.y); o.z = f2b(xv.z); o.w = f2b(xv.w);
    *(ushort4*)&xbp[h] = o;
    float xq[4] = {xv.x, xv.y, xv.z, xv.w};
#pragma unroll
    for (int q = 0; q < 4; ++q) {
      const float4* wp = (const float4*)&wr[(h + q) * 8];
      float4 w0 = wp[0], w1 = wp[1];
      acc[0] += xq[q] * w0.x; acc[1] += xq[q] * w0.y; acc[2] += xq[q] * w0.z; acc[3] += xq[q] * w0.w;
      acc[4] += xq[q] * w1.x; acc[5] += xq[q] * w1.y; acc[6] += xq[q] * w1.z; acc[7] += xq[q] * w1.w;
    }
  }
#pragma unroll
  for (int off = 32; off; off >>= 1)
#pragma unroll
    for (int e = 0; e < 8; ++e) acc[e] += __shfl_xor(acc[e], off, 64);
  if (lane == 0) {
    float l[8], p[8];
    float m = -1e30f;
#pragma unroll
    for (int e = 0; e < 8; ++e) { l[e] = acc[e] + br[e]; m = fmaxf(m, l[e]); }
    float s = 0.f;
#pragma unroll
    for (int e = 0; e < 8; ++e) { p[e] = __expf(l[e] - m); s += p[e]; }
    int i1 = 0;
#pragma unroll
    for (int e = 1; e < 8; ++e) if (p[e] > p[i1]) i1 = e;
    int i2 = (i1 == 0) ? 1 : 0;
#pragma unroll
    for (int e = 0; e < 8; ++e) if (e != i1 && p[e] > p[i2]) i2 = e;
    float ps = p[i1] + p[i2];
    eidx[t * 2]     = i1;  ew[t * 2]     = p[i1] / ps;
    eidx[t * 2 + 1] = i2;  ew[t * 2 + 1] = p[i2] / ps;
  }
}

// ---------------- router pass 2: compaction ----------------

__global__ __launch_bounds__(1024) void build_lists_kernel(
    const int* __restrict__ eidx, const float* ew,
    int* __restrict__ counts, int* __restrict__ tok2, float* __restrict__ wl,
    int* s2p) {
  int e = blockIdx.x;
  int tid = threadIdx.x;
  int lane = tid & 63, wv = tid >> 6;
  __shared__ int wsum[16];
  __shared__ int base;
  if (tid == 0) base = 0;
  __syncthreads();
  for (int c = 0; c < 2 * TOKENS; c += 1024) {
    int i = c + tid;
    bool m = (eidx[i] == e);
    unsigned long long bal = __ballot(m);
    if (lane == 0) wsum[wv] = __popcll(bal);
    __syncthreads();
    int wbase = base;
    for (int w = 0; w < wv; ++w) wbase += wsum[w];
    if (m) {
      int pos = wbase + __popcll(bal & ((1ull << lane) - 1ull));
      float w = ew[i];
      tok2[e * TOKENS + pos] = i;
      wl[e * TOKENS + pos] = w;
      s2p[i] = pos;
    }
    int total = 0;
#pragma unroll
    for (int w = 0; w < 16; ++w) total += wsum[w];
    __syncthreads();
    if (tid == 0) base += total;
    __syncthreads();
  }
  if (tid == 0) counts[e] = base;
}

// ---------------- gathered expert GEMM: 8-phase 256^2 BK=64 ----------------

#define MFMA_ROW(MH, MI, AF) \
  acc[(MH)*4+(MI)][0] = __builtin_amdgcn_mfma_f32_16x16x32_bf16(AF, bF0, acc[(MH)*4+(MI)][0], 0, 0, 0); \
  acc[(MH)*4+(MI)][1] = __builtin_amdgcn_mfma_f32_16x16x32_bf16(AF, bF1, acc[(MH)*4+(MI)][1], 0, 0, 0); \
  acc[(MH)*4+(MI)][2] = __builtin_amdgcn_mfma_f32_16x16x32_bf16(AF, bF2, acc[(MH)*4+(MI)][2], 0, 0, 0); \
  acc[(MH)*4+(MI)][3] = __builtin_amdgcn_mfma_f32_16x16x32_bf16(AF, bF3, acc[(MH)*4+(MI)][3], 0, 0, 0);

#define PHASE(KS, MH, STAGE_CODE, TRAIL_CODE) do { \
  const int abase_ = (cur * 2 + (KS)) * 8192; \
  const bf16x8 aF0 = *(const bf16x8*)&As[abase_ + (arow0 + (MH)*64 +  0) * 32 + cs8]; \
  const bf16x8 aF1 = *(const bf16x8*)&As[abase_ + (arow0 + (MH)*64 + 16) * 32 + cs8]; \
  const bf16x8 aF2 = *(const bf16x8*)&As[abase_ + (arow0 + (MH)*64 + 32) * 32 + cs8]; \
  const bf16x8 aF3 = *(const bf16x8*)&As[abase_ + (arow0 + (MH)*64 + 48) * 32 + cs8]; \
  const bf16x8 bF0 = *(const bf16x8*)&Bs[abase_ + (brow0 +  0) * 32 + cs8]; \
  const bf16x8 bF1 = *(const bf16x8*)&Bs[abase_ + (brow0 + 16) * 32 + cs8]; \
  const bf16x8 bF2 = *(const bf16x8*)&Bs[abase_ + (brow0 + 32) * 32 + cs8]; \
  const bf16x8 bF3 = *(const bf16x8*)&Bs[abase_ + (brow0 + 48) * 32 + cs8]; \
  STAGE_CODE; \
  asm volatile("" ::: "memory"); \
  __builtin_amdgcn_s_barrier(); \
  __builtin_amdgcn_s_setprio(1); \
  MFMA_ROW(MH, 0, aF0) \
  MFMA_ROW(MH, 1, aF1) \
  MFMA_ROW(MH, 2, aF2) \
  MFMA_ROW(MH, 3, aF3) \
  __builtin_amdgcn_s_setprio(0); \
  TRAIL_CODE; \
  asm volatile("" ::: "memory"); \
  __builtin_amdgcn_s_barrier(); \
} while (0)

__global__ __launch_bounds__(512, 2) void expert_gemm_kernel(
    const unsigned short* __restrict__ xb, const unsigned short* __restrict__ weT,
    const float* __restrict__ b_experts, const int* __restrict__ counts,
    const int* __restrict__ tok2, const float* __restrict__ wlist,
    unsigned short* __restrict__ outE) {
  int b = blockIdx.x;
  int e = b & 7;                        // expert -> XCD (blockIdx % 8)
  int tt = b >> 3;                      // 0..127
  int m0 = (tt >> 2) << 8;              // 32 m-tiles x 256 rows
  int n0 = (tt & 3) << 8;               // 4 n-tiles x 256 cols
  int cnt = counts[e];
  if (m0 >= cnt) return;
  int cbase = 0;
  for (int q = 0; q < e; ++q) cbase += counts[q];

  // LDS: [tilebuf 0/1][khalf 0/1][256 rows][32 k] for A and B (64KB each)
  __shared__ unsigned short As[2 * 2 * 8192];
  __shared__ unsigned short Bs[2 * 2 * 8192];
  __shared__ int   tokS[256];
  __shared__ float wS[256];

  int tid = threadIdx.x;
  if (tid < 256) {
    int r = m0 + tid;
    tokS[tid] = (r < cnt) ? tok2[e * TOKENS + r] : 0;
    wS[tid]   = (r < cnt) ? wlist[e * TOKENS + r] : 0.f;
  }
  __syncthreads();

  // staging: granule = [256 rows][32 k] bf16, 16KB, linear LDS.
  // thread t, li in {0,1}: g = li*512+t -> row g>>2, 16B chunk g&3.
  // source chunk = (g&3) ^ (row&3)  (inverse of the read swizzle).
  const unsigned short* wbase = weT + (size_t)e * (HDIM * DDIM);
  int g0 = tid, g1 = 512 + tid;
  int r0 = g0 >> 2, r1 = g1 >> 2;
  int sc0 = (((g0 & 3) ^ (r0 & 3)) << 3);
  int sc1 = (((g1 & 3) ^ (r1 & 3)) << 3);
  const unsigned short* aS0 = xb + (size_t)(tokS[r0] >> 1) * HDIM + sc0;
  const unsigned short* aS1 = xb + (size_t)(tokS[r1] >> 1) * HDIM + sc1;
  const unsigned short* bS0 = wbase + (size_t)(n0 + r0) * HDIM + sc0;
  const unsigned short* bS1 = wbase + (size_t)(n0 + r1) * HDIM + sc1;
  int du0 = (tid & ~63) * 8;            // wave-uniform LDS dest (elems)
  int du1 = (512 + (tid & ~63)) * 8;

  int wid = tid >> 6, lane = tid & 63;
  int wm = wid >> 2, wn = wid & 3;      // 2m x 4n waves, 128x64 out each
  int lr = lane & 15, quad = lane >> 4;
  int cs8 = ((quad ^ (lane & 3)) << 3); // read-side swizzled k-chunk (elems)
  int arow0 = wm * 128 + lr;
  int brow0 = wn * 64 + lr;

  f32x4 acc[8][4];
#pragma unroll
  for (int i = 0; i < 8; ++i)
#pragma unroll
    for (int j = 0; j < 4; ++j) acc[i][j] = (f32x4){0.f, 0.f, 0.f, 0.f};

  // prologue: A0[0],B0[0],A0[1],B0[1],A1[0],B1[0]  (kcol = kt*64 + kh*32)
  gld_lds16(aS0 +  0, &As[0 * 8192 + du0]); gld_lds16(aS1 +  0, &As[0 * 8192 + du1]);
  gld_lds16(bS0 +  0, &Bs[0 * 8192 + du0]); gld_lds16(bS1 +  0, &Bs[0 * 8192 + du1]);
  gld_lds16(aS0 + 32, &As[1 * 8192 + du0]); gld_lds16(aS1 + 32, &As[1 * 8192 + du1]);
  gld_lds16(bS0 + 32, &Bs[1 * 8192 + du0]); gld_lds16(bS1 + 32, &Bs[1 * 8192 + du1]);
  gld_lds16(aS0 + 64, &As[2 * 8192 + du0]); gld_lds16(aS1 + 64, &As[2 * 8192 + du1]);
  gld_lds16(bS0 + 64, &Bs[2 * 8192 + du0]); gld_lds16(bS1 + 64, &Bs[2 * 8192 + du1]);
  __syncthreads();                      // drains vmcnt: tiles 0 + half of 1 ready

  for (int t = 0; t < 16; ++t) {
    int cur = t & 1;
    // p0: khalf0, mhalf0 | stage A(t+1)[k1] into buf cur^1
    PHASE(0, 0,
      { if (t < 15) { int kc = (t + 1) * 64 + 32; int db = ((cur ^ 1) * 2 + 1) * 8192;
          gld_lds16(aS0 + kc, &As[db + du0]); gld_lds16(aS1 + kc, &As[db + du1]); } },
      { });
    // p1: khalf0, mhalf1 | stage B(t+1)[k1] | trail: vmcnt(4) (t=15: 0)
    PHASE(0, 1,
      { if (t < 15) { int kc = (t + 1) * 64 + 32; int db = ((cur ^ 1) * 2 + 1) * 8192;
          gld_lds16(bS0 + kc, &Bs[db + du0]); gld_lds16(bS1 + kc, &Bs[db + du1]); } },
      { if (t < 15) asm volatile("s_waitcnt vmcnt(4)" ::: "memory");
        else        asm volatile("s_waitcnt vmcnt(0)" ::: "memory"); });
    // p2: khalf1, mhalf0 | stage A(t+2)[k0] into buf cur (k0 dead after p1)
    PHASE(1, 0,
      { if (t < 14) { int kc = (t + 2) * 64; int db = (cur * 2) * 8192;
          gld_lds16(aS0 + kc, &As[db + du0]); gld_lds16(aS1 + kc, &As[db + du1]); } },
      { });
    // p3: khalf1, mhalf1 | stage B(t+2)[k0] | trail: vmcnt(8)
    PHASE(1, 1,
      { if (t < 14) { int kc = (t + 2) * 64; int db = (cur * 2) * 8192;
          gld_lds16(bS0 + kc, &Bs[db + du0]); gld_lds16(bS1 + kc, &Bs[db + du1]); } },
      { asm volatile("s_waitcnt vmcnt(8)" ::: "memory"); });
  }

  // epilogue: gelu * gate, dense stores into packed window
  int rowbase = cbase + m0;
#pragma unroll
  for (int ni = 0; ni < 4; ++ni) {
    int col = n0 + wn * 64 + ni * 16 + lr;
    float bias = b_experts[e * DDIM + col];
#pragma unroll
    for (int am = 0; am < 8; ++am) {
      int rb = wm * 128 + am * 16 + quad * 4;
#pragma unroll
      for (int r = 0; r < 4; ++r) {
        int row = rb + r;
        if (m0 + row < cnt) {
          float h = acc[am][ni][r] + bias;
          float z = 0.7978845608f * (h + 0.044715f * h * h * h);
          float tz = 1.f - 2.f / (__expf(2.f * z) + 1.f);
          float gg = 0.5f * h * (1.f + tz);
          outE[(size_t)(rowbase + row) * DDIM + col] = f2b(gg * wS[row]);
        }
      }
    }
  }
}

// ---------------- combine the two slots ----------------

__global__ void combine_kernel(const ushort4* __restrict__ outE,
                               const int* __restrict__ eidx, const int* __restrict__ s2p,
                               const int* __restrict__ counts,
                               ushort4* __restrict__ comb) {
  __shared__ int cbase[8];
  int tid = threadIdx.x;
  if (tid < 8) {
    int s = 0;
    for (int q = 0; q < tid; ++q) s += counts[q];
    cbase[tid] = s;
  }
  __syncthreads();
  int t = blockIdx.x;
  int d4 = tid;
  int i0 = t * 2, i1 = i0 + 1;
  size_t r0 = ((size_t)(cbase[eidx[i0]] + s2p[i0])) * 256 + d4;
  size_t r1 = ((size_t)(cbase[eidx[i1]] + s2p[i1])) * 256 + d4;
  ushort4 a = outE[r0];
  ushort4 b = outE[r1];
  ushort4 o;
  o.x = f2b(b2f(a.x) + b2f(b.x));
  o.y = f2b(b2f(a.y) + b2f(b.y));
  o.z = f2b(b2f(a.z) + b2f(b.z));
  o.w = f2b(b2f(a.w) + b2f(b.w));
  comb[t * 256 + d4] = o;
}

// ---------------- output projection GEMM (fp32 out) ----------------

__global__ __launch_bounds__(256, 3) void out_gemm_kernel(
    const unsigned short* __restrict__ Abf, const unsigned short* __restrict__ BT,
    const float* __restrict__ bias, float* __restrict__ out) {
  int b = blockIdx.x;
  int id = (b >> 3) + (b & 7) * 64;
  int n0 = (id >> 6) << 7;
  int m0 = (id & 63) << 7;

  __shared__ unsigned short As[3][128 * 32];
  __shared__ unsigned short Bs[3][128 * 32];
  int tid = threadIdx.x, wave = tid >> 6, lane = tid & 63;
  int subr = lane >> 2, koff = (lane & 3) * 8;

  const unsigned short* asrc[2];
  const unsigned short* bsrc[2];
  unsigned short* adst[3][2];
  unsigned short* bdst[3][2];
#pragma unroll
  for (int i = 0; i < 2; ++i) {
    int row = i * 64 + wave * 16 + subr;
    asrc[i] = Abf + (size_t)(m0 + row) * DDIM + koff;
    bsrc[i] = BT + (size_t)(n0 + row) * DDIM + koff;
#pragma unroll
    for (int bb = 0; bb < 3; ++bb) {
      adst[bb][i] = &As[bb][i * 2048 + wave * 512];
      bdst[bb][i] = &Bs[bb][i * 2048 + wave * 512];
    }
  }

  int wm = wave & 1, wn = wave >> 1;
  int quad = lane >> 4, lr = lane & 15;

  f32x4 zero = {0.f, 0.f, 0.f, 0.f};
  f32x4 acc[4][4];
#pragma unroll
  for (int i = 0; i < 4; ++i)
#pragma unroll
    for (int j = 0; j < 4; ++j) acc[i][j] = zero;

#pragma unroll
  for (int s = 0; s < 2; ++s)
#pragma unroll
    for (int i = 0; i < 2; ++i) {
      gld_lds16(asrc[i] + s * 32, adst[s][i]);
      gld_lds16(bsrc[i] + s * 32, bdst[s][i]);
    }

#pragma unroll
  for (int kk = 0; kk < 32; ++kk) {
    if (kk < 31) asm volatile("s_waitcnt vmcnt(4)" ::: "memory");
    else         asm volatile("s_waitcnt vmcnt(0)" ::: "memory");
    __builtin_amdgcn_s_barrier();
    if (kk + 2 < 32) {
      int nb = (kk + 2) % 3;
      int off = (kk + 2) * 32;
#pragma unroll
      for (int i = 0; i < 2; ++i) {
        gld_lds16(asrc[i] + off, adst[nb][i]);
        gld_lds16(bsrc[i] + off, bdst[nb][i]);
      }
    }
    int cb = kk % 3;
    bf16x8 af[4], bfr[4];
#pragma unroll
    for (int i = 0; i < 4; ++i)
      af[i] = *(const bf16x8*)&As[cb][(wm * 64 + i * 16 + lr) * 32 + quad * 8];
#pragma unroll
    for (int j = 0; j < 4; ++j)
      bfr[j] = *(const bf16x8*)&Bs[cb][(wn * 64 + j * 16 + lr) * 32 + quad * 8];
#pragma unroll
    for (int i = 0; i < 4; ++i)
#pragma unroll
      for (int j = 0; j < 4; ++j)
        acc[i][j] = __builtin_amdgcn_mfma_f32_16x16x32_bf16(af[i], bfr[j], acc[i][j], 0, 0, 0);
  }

#pragma unroll
  for (int j = 0; j < 4; ++j) {
    int col = n0 + wn * 64 + j * 16 + lr;
    float bs = bias[col];
#pragma unroll
    for (int i = 0; i < 4; ++i) {
      int rbase = wm * 64 + i * 16 + quad * 4;
#pragma unroll
      for (int r = 0; r < 4; ++r)
        out[(size_t)(m0 + rbase + r) * DDIM + col] = acc[i][j][r] + bs;
    }
  }
}

// ---------------- launch ----------------

extern "C" void kernel_launch(void* const* d_in, const int* in_sizes, int n_in,
                              void* d_out, int out_size, void* d_ws, size_t ws_size,
                              hipStream_t stream) {
  const float* x  = (const float*)d_in[0];
  const float* wr = (const float*)d_in[1];
  const float* br = (const float*)d_in[2];
  const float* we = (const float*)d_in[3];
  const float* be = (const float*)d_in[4];
  const float* wo = (const float*)d_in[5];
  const float* bo = (const float*)d_in[6];
  float* out = (float*)d_out;

  char* ws = (char*)d_ws;
  unsigned short* xb      = (unsigned short*)(ws);                  // 16 MB
  unsigned short* weT     = (unsigned short*)(ws + 16777216);       // 16 MB
  unsigned short* woT     = (unsigned short*)(ws + 33554432);       //  2 MB
  unsigned short* outE    = (unsigned short*)(ws + 35651584);       // 32 MB
  int*            counts  = (int*)           (ws + 69206016);       // 256 B
  int*            tok2    = (int*)           (ws + 69206272);       // 256 KB
  float*          wlist   = (float*)         (ws + 69468416);       // 256 KB
  int*            eidx    = (int*)           (ws + 69730560);       // 64 KB
  float*          ew      = (float*)         (ws + 69796096);       // 64 KB
  int*            s2p     = (int*)ew;  // alias: ew dead after build_lists
  unsigned short* comb    = xb;        // alias: xb dead after expert_gemm

  router_compute_kernel<<<2048, 256, 0, stream>>>(x, wr, br, eidx, ew, xb);
  transpose_cvt_kernel<<<dim3(32, 32, 9), dim3(32, 8), 0, stream>>>(we, wo, weT, woT);
  build_lists_kernel<<<8, 1024, 0, stream>>>(eidx, ew, counts, tok2, wlist, s2p);
  expert_gemm_kernel<<<1024, 512, 0, stream>>>(xb, weT, be, counts, tok2, wlist, outE);
  combine_kernel<<<8192, 256, 0, stream>>>((const ushort4*)outE, eidx, s2p, counts, (ushort4*)comb);
  out_gemm_kernel<<<512, 256, 0, stream>>>(comb, woT, bo, out);
}